// Round 1
// baseline (536.341 us; speedup 1.0000x reference)
//
#include <hip/hip_runtime.h>
#include <cstdint>

// Problem constants (fixed by the reference setup_inputs)
#define BB   2
#define LL   2048
#define HH   8
#define EE   64
#define DIAG 64
#define BAND 127   // 2*DIAG - 1 valid band offsets per row

// One 128-thread block per (b, h, i) row.
__global__ __launch_bounds__(128) void anomaly_attn_kernel(
    const float* __restrict__ Q,   // [B, L, H, E]
    const float* __restrict__ K,   // [B, L, H, E]
    const float* __restrict__ V,   // [B, L, H, E]
    float* __restrict__ outV,      // [B, L, H, E]
    float* __restrict__ outS)      // [B, H, L, L]
{
    __shared__ float lds_q[EE];
    __shared__ float lds_s[128];   // band softmax probs (0 for invalid slots)
    __shared__ float lds_red[4];
    __shared__ float lds_v[EE];

    const int bid  = blockIdx.x;
    const int i    = bid & (LL - 1);
    const int h    = (bid >> 11) & (HH - 1);
    const int b    = bid >> 14;
    const int t    = threadIdx.x;
    const int wave = t >> 6;
    const int lane = t & 63;

    // ---- Phase 1: stage q row in LDS ----
    if (t < EE)
        lds_q[t] = Q[(((size_t)(b * LL + i)) * HH + h) * EE + t];
    __syncthreads();

    // ---- Phase 2: band scores. Thread t -> column j = i-63+t ----
    const int  j     = i - (DIAG - 1) + t;
    const bool valid = (t < BAND) && (j >= 0) && (j < LL);
    float s = 0.f;
    if (valid) {
        const float4* kp = (const float4*)(K + (((size_t)(b * LL + j)) * HH + h) * EE);
        const float4* qp = (const float4*)lds_q;
#pragma unroll
        for (int c = 0; c < EE / 4; ++c) {
            float4 kv = kp[c];
            float4 qv = qp[c];
            s += qv.x * kv.x + qv.y * kv.y + qv.z * kv.z + qv.w * kv.w;
        }
    }
    const float scale = 0.125f;  // 1/sqrt(64)
    float sc = valid ? s * scale : -3.0e38f;

    // ---- Phase 3: softmax across the 127 band entries (2 waves) ----
    float m = sc;
#pragma unroll
    for (int off = 32; off > 0; off >>= 1)
        m = fmaxf(m, __shfl_xor(m, off, 64));
    if (lane == 0) lds_red[wave] = m;
    __syncthreads();
    m = fmaxf(lds_red[0], lds_red[1]);

    float p = valid ? __expf(sc - m) : 0.f;
    float l = p;
#pragma unroll
    for (int off = 32; off > 0; off >>= 1)
        l += __shfl_xor(l, off, 64);
    if (lane == 0) lds_red[2 + wave] = l;
    __syncthreads();
    l = lds_red[2] + lds_red[3];

    lds_s[t] = p / l;   // exact 0 for invalid slots (p==0)
    __syncthreads();

    // ---- Phase 4: write full series row (zeros outside band), coalesced f4 ----
    {
        float4* srow4 = (float4*)(outS + ((((size_t)(b * HH + h)) * LL + i) * LL));
        const int dbase = (DIAG - 1) - i;  // d = col + dbase indexes lds_s
#pragma unroll
        for (int c = 0; c < 4; ++c) {
            const int col0 = t * 16 + c * 4;
            const int d0   = col0 + dbase;
            float4 v;
            v.x = ((unsigned)(d0 + 0) < (unsigned)BAND) ? lds_s[d0 + 0] : 0.f;
            v.y = ((unsigned)(d0 + 1) < (unsigned)BAND) ? lds_s[d0 + 1] : 0.f;
            v.z = ((unsigned)(d0 + 2) < (unsigned)BAND) ? lds_s[d0 + 2] : 0.f;
            v.w = ((unsigned)(d0 + 3) < (unsigned)BAND) ? lds_s[d0 + 3] : 0.f;
            srow4[t * 4 + c] = v;
        }
    }

    // ---- Phase 5: V_out[i, :] = sum_j series[i,j] * V[j, :]; waves split j ----
    {
        const int e  = lane;
        const int t0 = wave * 64;
        const int t1 = (wave == 0) ? 64 : BAND;
        int lo = t0, hi = t1;
        // jj = i - 63 + tt must be in [0, LL)
        if ((DIAG - 1) - i > lo) lo = (DIAG - 1) - i;
        if (LL - i + (DIAG - 1) < hi) hi = LL - i + (DIAG - 1);

        float acc = 0.f;
        if (lo < hi) {
            const float* vp = V + (((size_t)(b * LL + (i - (DIAG - 1) + lo))) * HH + h) * EE + e;
            for (int tt = lo; tt < hi; ++tt) {
                acc += lds_s[tt] * (*vp);
                vp += HH * EE;
            }
        }
        if (wave == 1) lds_v[e] = acc;
        __syncthreads();
        if (wave == 0)
            outV[(((size_t)(b * LL + i)) * HH + h) * EE + e] = acc + lds_v[e];
    }
}

extern "C" void kernel_launch(void* const* d_in, const int* in_sizes, int n_in,
                              void* d_out, int out_size, void* d_ws, size_t ws_size,
                              hipStream_t stream) {
    const float* Q = (const float*)d_in[0];
    const float* K = (const float*)d_in[1];
    const float* V = (const float*)d_in[2];
    // d_in[3] = sigma (unused by reference), d_in[4] = attn_mask (unused)

    float* outV = (float*)d_out;                                   // [B,L,H,E]
    float* outS = (float*)d_out + (size_t)BB * LL * HH * EE;       // [B,H,L,L]

    const int grid = BB * HH * LL;  // 32768 blocks
    anomaly_attn_kernel<<<grid, 128, 0, stream>>>(Q, K, V, outV, outS);
}

// Round 2
// 467.504 us; speedup vs baseline: 1.1472x; 1.1472x over previous
//
#include <hip/hip_runtime.h>
#include <cstdint>

// Problem constants (fixed by the reference setup_inputs)
#define BB   2
#define LL   2048
#define HH   8
#define EE   64
#define DIAG 64
#define BAND 127   // 2*DIAG - 1 valid band offsets per row

// One 128-thread block per (b, h, i) row. 32768 blocks total.
__global__ __launch_bounds__(128) void anomaly_attn_kernel(
    const float* __restrict__ Q,   // [B, L, H, E]
    const float* __restrict__ K,   // [B, L, H, E]
    const float* __restrict__ V,   // [B, L, H, E]
    float* __restrict__ outV,      // [B, L, H, E]
    float* __restrict__ outS)      // [B, H, L, L]
{
    __shared__ float  lds_q[EE];
    __shared__ float  lds_s[128];   // band softmax probs (0 for invalid slots)
    __shared__ float  lds_red[4];
    __shared__ float4 lds_v[16];

    // XCD-aware swizzle: blocks dispatch round-robin over 8 XCDs (bid % 8).
    // Give each XCD a contiguous 4096-row chunk so the K/V band window
    // (~130 KB) stays resident in that XCD's L2/L1 instead of thrashing L3.
    const int bid  = blockIdx.x;
    const int grow = (bid & 7) * 4096 + (bid >> 3);   // global row id
    const int i    = grow & (LL - 1);
    const int h    = (grow >> 11) & (HH - 1);
    const int b    = grow >> 14;
    const int t    = threadIdx.x;
    const int wave = t >> 6;
    const int lane = t & 63;

    // ---- Phase 1: stage q row in LDS (16 lanes x float4) ----
    if (t < EE / 4)
        ((float4*)lds_q)[t] = ((const float4*)(Q + (((size_t)(b * LL + i)) * HH + h) * EE))[t];
    __syncthreads();

    // ---- Phase 2: band scores. Thread t -> column j = i-63+t ----
    const int  j     = i - (DIAG - 1) + t;
    const bool valid = (t < BAND) && (j >= 0) && (j < LL);
    float s = 0.f;
    if (valid) {
        const float4* kp = (const float4*)(K + (((size_t)(b * LL + j)) * HH + h) * EE);
        const float4* qp = (const float4*)lds_q;
#pragma unroll
        for (int c = 0; c < EE / 4; ++c) {
            float4 kv = kp[c];
            float4 qv = qp[c];
            s += qv.x * kv.x + qv.y * kv.y + qv.z * kv.z + qv.w * kv.w;
        }
    }
    const float scale = 0.125f;  // 1/sqrt(64)
    float sc = valid ? s * scale : -3.0e38f;

    // ---- Phase 3: softmax across the 127 band entries (2 waves) ----
    float m = sc;
#pragma unroll
    for (int off = 32; off > 0; off >>= 1)
        m = fmaxf(m, __shfl_xor(m, off, 64));
    if (lane == 0) lds_red[wave] = m;
    __syncthreads();
    m = fmaxf(lds_red[0], lds_red[1]);

    float p = valid ? __expf(sc - m) : 0.f;
    float l = p;
#pragma unroll
    for (int off = 32; off > 0; off >>= 1)
        l += __shfl_xor(l, off, 64);
    if (lane == 0) lds_red[2 + wave] = l;
    __syncthreads();
    l = lds_red[2] + lds_red[3];

    lds_s[t] = p / l;   // exact 0 for invalid slots (p==0), incl. t==127
    __syncthreads();

    // ---- Phase 4: write full series row (zeros outside band), coalesced f4 ----
    {
        float4* srow4 = (float4*)(outS + ((((size_t)(b * HH + h)) * LL + i) * LL));
        const int dbase = (DIAG - 1) - i;  // d = col + dbase indexes lds_s
#pragma unroll
        for (int c = 0; c < 4; ++c) {
            const int col0 = t * 16 + c * 4;
            const int d0   = col0 + dbase;
            float4 v;
            v.x = ((unsigned)(d0 + 0) < (unsigned)BAND) ? lds_s[d0 + 0] : 0.f;
            v.y = ((unsigned)(d0 + 1) < (unsigned)BAND) ? lds_s[d0 + 1] : 0.f;
            v.z = ((unsigned)(d0 + 2) < (unsigned)BAND) ? lds_s[d0 + 2] : 0.f;
            v.w = ((unsigned)(d0 + 3) < (unsigned)BAND) ? lds_s[d0 + 3] : 0.f;
            srow4[t * 4 + c] = v;
        }
    }

    // ---- Phase 5: V_out[i,:] = sum_j series[i,j] * V[j,:]  (vectorized) ----
    // Lane layout: j_sub = lane>>4 (4 j's per wave-pass), e4 = lane&15
    // (each lane owns 4 contiguous e columns as a float4).
    // 8 j-slots per iteration (2 waves x 4), fixed 16 iterations cover
    // slots 0..127; invalid slots have weight 0, address clamped to stay legal.
    {
        const int e4    = lane & 15;
        const int j_sub = lane >> 4;
        const float* vbase = V + ((size_t)b * LL * HH + h) * EE + e4 * 4;

        float4 acc = make_float4(0.f, 0.f, 0.f, 0.f);
#pragma unroll
        for (int iter = 0; iter < 16; ++iter) {
            const int slot = iter * 8 + wave * 4 + j_sub;   // 0..127
            int jj = i - (DIAG - 1) + slot;
            int jc = jj < 0 ? 0 : (jj > LL - 1 ? LL - 1 : jj);
            const float w = lds_s[slot];
            float4 vv = *(const float4*)(vbase + (size_t)jc * HH * EE);
            acc.x += w * vv.x;
            acc.y += w * vv.y;
            acc.z += w * vv.z;
            acc.w += w * vv.w;
        }
        // reduce over j_sub (lanes l, l^16, l^32, l^48 share e4)
#pragma unroll
        for (int off = 16; off <= 32; off <<= 1) {
            acc.x += __shfl_xor(acc.x, off, 64);
            acc.y += __shfl_xor(acc.y, off, 64);
            acc.z += __shfl_xor(acc.z, off, 64);
            acc.w += __shfl_xor(acc.w, off, 64);
        }
        if (wave == 1 && lane < 16) lds_v[e4] = acc;
        __syncthreads();
        if (wave == 0 && lane < 16) {
            float4 o = lds_v[e4];
            o.x += acc.x; o.y += acc.y; o.z += acc.z; o.w += acc.w;
            ((float4*)(outV + (((size_t)(b * LL + i)) * HH + h) * EE))[e4] = o;
        }
    }
}

extern "C" void kernel_launch(void* const* d_in, const int* in_sizes, int n_in,
                              void* d_out, int out_size, void* d_ws, size_t ws_size,
                              hipStream_t stream) {
    const float* Q = (const float*)d_in[0];
    const float* K = (const float*)d_in[1];
    const float* V = (const float*)d_in[2];
    // d_in[3] = sigma (unused by reference), d_in[4] = attn_mask (unused)

    float* outV = (float*)d_out;                                   // [B,L,H,E]
    float* outS = (float*)d_out + (size_t)BB * LL * HH * EE;       // [B,H,L,L]

    const int grid = BB * HH * LL;  // 32768 blocks
    anomaly_attn_kernel<<<grid, 128, 0, stream>>>(Q, K, V, outV, outS);
}

// Round 3
// 346.675 us; speedup vs baseline: 1.5471x; 1.3485x over previous
//
#include <hip/hip_runtime.h>
#include <cstdint>

// Problem constants (fixed by the reference setup_inputs)
#define BB    2
#define LL    2048
#define HH    8
#define EE    64
#define DIAG  64
#define BAND  127        // 2*DIAG - 1 valid band offsets per row
#define RR    16         // output rows per block
#define TILE  143        // K/V tile rows staged: RR + 2*(DIAG-1) = 142, +1 pad row
#define SK    68         // padded tile row stride in floats (breaks 32-bank conflicts)
#define NT    256        // threads per block (4 waves)

// One 256-thread block per 16 consecutive rows of one (b,h). 2048 blocks.
__global__ __launch_bounds__(NT, 3) void anomaly_attn_kernel(
    const float* __restrict__ Q,   // [B, L, H, E]
    const float* __restrict__ K,   // [B, L, H, E]
    const float* __restrict__ V,   // [B, L, H, E]
    float* __restrict__ outV,      // [B, L, H, E]
    float* __restrict__ outS)      // [B, H, L, L]
{
    __shared__ float lds_kv[TILE * SK];   // K tile, later reused as V tile (38.9 KB)
    __shared__ float lds_s[RR * 128];     // softmax probs, slot 127 == 0 (8 KB)
    __shared__ float lds_q[RR * EE];      // Q tile (4 KB)

    // XCD swizzle: give each XCD a contiguous run of row-blocks so the K/V
    // window + outS write stream stay local to one XCD's L2.
    const int bid  = blockIdx.x;
    const int gblk = (bid & 7) * 256 + (bid >> 3);   // [0, 2048)
    const int rb   = gblk & 127;
    const int h    = (gblk >> 7) & 7;
    const int b    = gblk >> 10;
    const int i0   = rb * RR;

    const int t    = threadIdx.x;
    const int wave = t >> 6;
    const int lane = t & 63;

    const size_t headOff = ((size_t)b * LL * HH + h) * EE;  // + j*HH*EE per row
    const int    rowStr  = HH * EE;                         // 512 floats between rows

    // ---- Phase A: stage Q tile (coalesced) + K tile (coalesced) ----
    {
        const int qrow = t >> 4, qf = t & 15;
        ((float4*)lds_q)[t] =
            *(const float4*)(Q + headOff + (size_t)(i0 + qrow) * rowStr + qf * 4);

        for (int idx = t; idx < TILE * 16; idx += NT) {
            const int trow = idx >> 4, tf = idx & 15;
            int j = i0 - (DIAG - 1) + trow;
            j = j < 0 ? 0 : (j > LL - 1 ? LL - 1 : j);
            float4 kv = *(const float4*)(K + headOff + (size_t)j * rowStr + tf * 4);
            *(float4*)(lds_kv + trow * SK + tf * 4) = kv;
        }
    }
    __syncthreads();

    // ---- Phase B+C: scores + softmax. Wave w owns rows 4w..4w+3.        ----
    // Lane owns column slots {lane, lane+64}; full dot per lane, no reduce.
    const float scale = 0.125f;   // 1/sqrt(64)
    for (int r4 = 0; r4 < 4; ++r4) {
        const int r = wave * 4 + r4;
        const int i = i0 + r;
        const float* qrow = lds_q + r * EE;
        const float* k1   = lds_kv + (r + lane) * SK;        // slot = lane
        const float* k2   = k1 + 64 * SK;                    // slot = lane + 64
        float s1 = 0.f, s2 = 0.f;
#pragma unroll
        for (int c = 0; c < 16; ++c) {
            const float4 q4 = *(const float4*)(qrow + c * 4);   // broadcast
            const float4 a4 = *(const float4*)(k1 + c * 4);
            const float4 b4 = *(const float4*)(k2 + c * 4);
            s1 += q4.x * a4.x + q4.y * a4.y + q4.z * a4.z + q4.w * a4.w;
            s2 += q4.x * b4.x + q4.y * b4.y + q4.z * b4.z + q4.w * b4.w;
        }
        const int  slot2 = lane + 64;
        const bool v1 = (i - (DIAG - 1) + lane) >= 0;                 // j1 in [0,L)
        const bool v2 = (slot2 < BAND) && (i - (DIAG - 1) + slot2 < LL);
        float sc1 = v1 ? s1 * scale : -3.0e38f;
        float sc2 = v2 ? s2 * scale : -3.0e38f;

        float m = fmaxf(sc1, sc2);
#pragma unroll
        for (int off = 1; off < 64; off <<= 1)
            m = fmaxf(m, __shfl_xor(m, off, 64));
        float p1 = v1 ? __expf(sc1 - m) : 0.f;
        float p2 = v2 ? __expf(sc2 - m) : 0.f;
        float l = p1 + p2;
#pragma unroll
        for (int off = 1; off < 64; off <<= 1)
            l += __shfl_xor(l, off, 64);
        const float inv = 1.0f / l;
        lds_s[r * 128 + lane]  = p1 * inv;
        lds_s[r * 128 + slot2] = p2 * inv;   // slot 127 -> exact 0
    }
    __syncthreads();   // all waves done reading lds_kv (K)

    // ---- Phase A2: stage V tile into the same LDS buffer ----
    for (int idx = t; idx < TILE * 16; idx += NT) {
        const int trow = idx >> 4, tf = idx & 15;
        int j = i0 - (DIAG - 1) + trow;
        j = j < 0 ? 0 : (j > LL - 1 ? LL - 1 : j);
        float4 vv = *(const float4*)(V + headOff + (size_t)j * rowStr + tf * 4);
        *(float4*)(lds_kv + trow * SK + tf * 4) = vv;
    }
    __syncthreads();

    // ---- Phase D: store full series rows (zeros outside band), coalesced ----
    for (int r4 = 0; r4 < 4; ++r4) {
        const int r = wave * 4 + r4;
        const int i = i0 + r;
        float4* srow4 = (float4*)(outS + (((size_t)(b * HH + h)) * LL + i) * LL);
        const int start = i - (DIAG - 1);
        const float* sp = lds_s + r * 128;
#pragma unroll
        for (int k = 0; k < 8; ++k) {
            const int col4 = lane + k * 64;
            const int d0   = col4 * 4 - start;   // slot index of component .x
            float4 v = make_float4(0.f, 0.f, 0.f, 0.f);
            if (d0 + 3 >= 0 && d0 <= BAND - 1) {   // any component in band
                int ix = d0;
                int i0c = ix < 0 ? 0 : (ix > 127 ? 127 : ix);
                int i1c = ix + 1 < 0 ? 0 : (ix + 1 > 127 ? 127 : ix + 1);
                int i2c = ix + 2 < 0 ? 0 : (ix + 2 > 127 ? 127 : ix + 2);
                int i3c = ix + 3 < 0 ? 0 : (ix + 3 > 127 ? 127 : ix + 3);
                v.x = (ix     >= 0) ? sp[i0c] : 0.f;   // slot 127 holds 0
                v.y = (ix + 1 >= 0) ? sp[i1c] : 0.f;
                v.z = (ix + 2 >= 0) ? sp[i2c] : 0.f;
                v.w = (ix + 3 >= 0) ? sp[i3c] : 0.f;
            }
            srow4[col4] = v;
        }
    }

    // ---- Phase E: V_out[i,:] = sum_s probs[s] * V[i-63+s, :] from LDS ----
    {
        const int e4   = lane & 15;
        const int jsub = lane >> 4;
        for (int r4 = 0; r4 < 4; ++r4) {
            const int r = wave * 4 + r4;
            const int i = i0 + r;
            const float* sp = lds_s + r * 128;
            float4 acc = make_float4(0.f, 0.f, 0.f, 0.f);
#pragma unroll
            for (int p = 0; p < 32; ++p) {
                const int   slot = p * 4 + jsub;          // 0..127; 127 has w=0
                const float w    = sp[slot];
                const float4 vv  = *(const float4*)(lds_kv + (r + slot) * SK + e4 * 4);
                acc.x += w * vv.x;
                acc.y += w * vv.y;
                acc.z += w * vv.z;
                acc.w += w * vv.w;
            }
#pragma unroll
            for (int off = 16; off <= 32; off <<= 1) {
                acc.x += __shfl_xor(acc.x, off, 64);
                acc.y += __shfl_xor(acc.y, off, 64);
                acc.z += __shfl_xor(acc.z, off, 64);
                acc.w += __shfl_xor(acc.w, off, 64);
            }
            if (lane < 16)
                ((float4*)(outV + headOff + (size_t)i * rowStr))[e4] = acc;
        }
    }
}

extern "C" void kernel_launch(void* const* d_in, const int* in_sizes, int n_in,
                              void* d_out, int out_size, void* d_ws, size_t ws_size,
                              hipStream_t stream) {
    const float* Q = (const float*)d_in[0];
    const float* K = (const float*)d_in[1];
    const float* V = (const float*)d_in[2];
    // d_in[3] = sigma (unused by reference), d_in[4] = attn_mask (unused)

    float* outV = (float*)d_out;                                   // [B,L,H,E]
    float* outS = (float*)d_out + (size_t)BB * LL * HH * EE;       // [B,H,L,L]

    const int grid = (BB * HH * LL) / RR;  // 2048 blocks
    anomaly_attn_kernel<<<grid, NT, 0, stream>>>(Q, K, V, outV, outS);
}